// Round 1
// baseline (882.454 us; speedup 1.0000x reference)
//
#include <hip/hip_runtime.h>

// ReLU_Feat_Posenc: bilinear gather (512x512x100) + posenc(16 freq) + MLP 166->128x4->3
// Strategy: f16 MFMA (32x32x16) MLP fused with gather/posenc; weights pre-transposed
// to f16 in ws; features pre-cast to f16 [512][512][112] in ws (halves gather bytes).
// Precision: f16 in / fp32 MFMA accumulate -> ~1e-4 abs err vs 1.11e-3 threshold.

#define GN    512
#define CELL  112   // padded f16 feature vector per grid cell
#define KP0   192   // padded K for layer 0 (feat 0..111, posenc 112..177, zero 178..191)
#define STR0  200   // LDS X stride (f16) -> 100 dwords/row, %32=4: conflict-free
#define STR1  136   // LDS h stride (f16) -> 68 dwords/row, %32=4
#define TP    64    // points per block

typedef _Float16 half8  __attribute__((ext_vector_type(8)));
typedef _Float16 half4v __attribute__((ext_vector_type(4)));
typedef float    f4     __attribute__((ext_vector_type(4)));
typedef float    f16v   __attribute__((ext_vector_type(16)));

// ws layout (f16 elems): [0,24576) Wt0[128][192]; then 3x Wt[128][128]; total 73728.
// features f16 [512*512][112] at elem offset 73728 (byte 147456).

__global__ __launch_bounds__(256) void k_weights(
    const float* __restrict__ W0, const float* __restrict__ W1,
    const float* __restrict__ W2, const float* __restrict__ W3,
    _Float16* __restrict__ wt) {
  int t = blockIdx.x * 256 + threadIdx.x;  // 288 blocks * 256 = 73728 exact
  float v;
  if (t < 24576) {                 // Wt0[n][k'], k' permuted: X col order
    int n = t / 192, k = t - n * 192;
    if (k < 100)      v = W0[(66 + k) * 128 + n];        // feat rows of W0
    else if (k < 112) v = 0.0f;                          // feat pad
    else if (k < 178) v = W0[(k - 112) * 128 + n];       // posenc rows
    else              v = 0.0f;                          // K pad
  } else {
    int u = t - 24576;
    int l = u >> 14, r = u & 16383;
    int n = r >> 7, k = r & 127;
    const float* W = (l == 0) ? W1 : (l == 1) ? W2 : W3;
    v = W[k * 128 + n];
  }
  wt[t] = (_Float16)v;
}

__global__ __launch_bounds__(256) void k_feat(const float* __restrict__ F,
                                              _Float16* __restrict__ out) {
  int e = blockIdx.x * 256 + threadIdx.x;  // 28672 blocks: cell*28 + j4, exact
  int cell = e / 28, j4 = e - cell * 28;
  half4v o;
  if (j4 < 25) {
    f4 f = *(const f4*)(F + (size_t)cell * 100 + j4 * 4);
    o[0] = (_Float16)f[0]; o[1] = (_Float16)f[1];
    o[2] = (_Float16)f[2]; o[3] = (_Float16)f[3];
  } else {
    o[0] = o[1] = o[2] = o[3] = (_Float16)0.0f;
  }
  *(half4v*)(out + (size_t)cell * CELL + j4 * 4) = o;
}

__device__ __forceinline__ void layer128(const _Float16* in, _Float16* outb,
    const _Float16* __restrict__ Wt, const float* __restrict__ bv,
    int row, int n0, int n1, int kh, int mrow) {
  half8 B0[8], B1[8];
#pragma unroll
  for (int ks = 0; ks < 8; ++ks) {
    B0[ks] = *(const half8*)(Wt + n0 * 128 + ks * 16 + kh * 8);
    B1[ks] = *(const half8*)(Wt + n1 * 128 + ks * 16 + kh * 8);
  }
  float bi0 = bv[n0], bi1 = bv[n1];
  f16v a0, a1;
#pragma unroll
  for (int i = 0; i < 16; ++i) { a0[i] = bi0; a1[i] = bi1; }
#pragma unroll
  for (int ks = 0; ks < 8; ++ks) {
    half8 A = *(const half8*)(in + row * STR1 + ks * 16 + kh * 8);
    a0 = __builtin_amdgcn_mfma_f32_32x32x16_f16(A, B0[ks], a0, 0, 0, 0);
    a1 = __builtin_amdgcn_mfma_f32_32x32x16_f16(A, B1[ks], a1, 0, 0, 0);
  }
#pragma unroll
  for (int r = 0; r < 16; ++r) {   // C: col=lane&31, row=(r&3)+8*(r>>2)+4*kh
    int rr = mrow + (r & 3) + 8 * (r >> 2) + 4 * kh;
    float z0 = a0[r]; z0 = z0 > 0.f ? z0 : 0.01f * z0;
    float z1 = a1[r]; z1 = z1 > 0.f ? z1 : 0.01f * z1;
    outb[rr * STR1 + n0] = (_Float16)z0;
    outb[rr * STR1 + n1] = (_Float16)z1;
  }
}

template <bool F16F>
__global__ __launch_bounds__(256) void k_main(
    const float* __restrict__ UV, const float* __restrict__ FEA,
    const _Float16* __restrict__ wt, const _Float16* __restrict__ feat16,
    const float* __restrict__ b0, const float* __restrict__ b1,
    const float* __restrict__ b2, const float* __restrict__ b3,
    const float* __restrict__ W4, const float* __restrict__ b4,
    float* __restrict__ out) {
  __shared__ _Float16 bufA[TP * STR0] __attribute__((aligned(16)));  // 25600 B
  __shared__ _Float16 bufB[TP * STR1] __attribute__((aligned(16)));  // 17408 B
  const int t = threadIdx.x;
  const int p = t & 63;        // point within tile
  const int q = t >> 6;        // wave id / task quarter
  const int gp = blockIdx.x * TP + p;
  float2 uv = *(const float2*)(UV + 2 * (size_t)gp);
  const float U = uv.x, V = uv.y;

  // ---------------- posenc (cols 112..177) ----------------
  if (q == 0) {
    bufA[p * STR0 + 112] = (_Float16)U;
    bufA[p * STR0 + 113] = (_Float16)V;
#pragma unroll
    for (int c = 178; c < 192; ++c) bufA[p * STR0 + c] = (_Float16)0.0f;
  }
  const float inv2pi = 0.15915494309189535f;
  const float twopi  = 6.283185307179586f;
#pragma unroll
  for (int fi = 0; fi < 4; ++fi) {
    int f = 4 * q + fi;
    float kk = (float)(1 << f);
    float ru = kk * U * inv2pi; ru -= floorf(ru);
    float rv = kk * V * inv2pi; rv -= floorf(rv);
    float su = __sinf(ru * twopi), cu = __cosf(ru * twopi);
    float sv = __sinf(rv * twopi), cv = __cosf(rv * twopi);
    int cbase = p * STR0 + 114 + 4 * f;
    bufA[cbase + 0] = (_Float16)su;
    bufA[cbase + 1] = (_Float16)sv;
    bufA[cbase + 2] = (_Float16)cu;
    bufA[cbase + 3] = (_Float16)cv;
  }

  // ---------------- bilinear gather (cols 0..111) ----------------
  {
    float iu = 511.0f * U, iv = 511.0f * V;
    float fu0 = floorf(iu), fv0 = floorf(iv);
    int iU0 = (int)fu0, iV0 = (int)fv0;
    int iU1 = (int)ceilf(iu), iV1 = (int)ceilf(iv);
    float fu = iu - fu0, fv = iv - fv0;
    float w00 = (1.f - fu) * (1.f - fv);
    float w10 = fu * (1.f - fv);
    float w01 = (1.f - fu) * fv;
    float w11 = fu * fv;
    int j0 = (q < 2) ? 4 * q : 8 + 3 * (q - 2);   // chunks {0-3}{4-7}{8-10}{11-13}
    int j1 = (q < 2) ? j0 + 4 : j0 + 3;
    if constexpr (F16F) {
      const half8* c00 = (const half8*)(feat16 + (size_t)(iU0 * GN + iV0) * CELL);
      const half8* c01 = (const half8*)(feat16 + (size_t)(iU0 * GN + iV1) * CELL);
      const half8* c10 = (const half8*)(feat16 + (size_t)(iU1 * GN + iV0) * CELL);
      const half8* c11 = (const half8*)(feat16 + (size_t)(iU1 * GN + iV1) * CELL);
      for (int j = j0; j < j1; ++j) {
        half8 a = c00[j], b = c01[j], c = c10[j], d = c11[j];
        half8 o;
#pragma unroll
        for (int e = 0; e < 8; ++e) {
          float vv = w00 * (float)a[e] + w01 * (float)b[e] +
                     w10 * (float)c[e] + w11 * (float)d[e];
          o[e] = (_Float16)vv;
        }
        *(half8*)&bufA[p * STR0 + 8 * j] = o;
      }
    } else {
      const float* r00 = FEA + (size_t)(iU0 * GN + iV0) * 100;
      const float* r01 = FEA + (size_t)(iU0 * GN + iV1) * 100;
      const float* r10 = FEA + (size_t)(iU1 * GN + iV0) * 100;
      const float* r11 = FEA + (size_t)(iU1 * GN + iV1) * 100;
      for (int j = j0; j < j1; ++j) {
        float o[8];
        if (j < 12) {
#pragma unroll
          for (int hh = 0; hh < 2; ++hh) {
            f4 a = *(const f4*)(r00 + 8 * j + 4 * hh);
            f4 b = *(const f4*)(r01 + 8 * j + 4 * hh);
            f4 c = *(const f4*)(r10 + 8 * j + 4 * hh);
            f4 d = *(const f4*)(r11 + 8 * j + 4 * hh);
#pragma unroll
            for (int e = 0; e < 4; ++e)
              o[4 * hh + e] = w00 * a[e] + w01 * b[e] + w10 * c[e] + w11 * d[e];
          }
        } else if (j == 12) {   // feats 96..99 + zero pad
          f4 a = *(const f4*)(r00 + 96);
          f4 b = *(const f4*)(r01 + 96);
          f4 c = *(const f4*)(r10 + 96);
          f4 d = *(const f4*)(r11 + 96);
#pragma unroll
          for (int e = 0; e < 4; ++e)
            o[e] = w00 * a[e] + w01 * b[e] + w10 * c[e] + w11 * d[e];
          o[4] = o[5] = o[6] = o[7] = 0.f;
        } else {
#pragma unroll
          for (int e = 0; e < 8; ++e) o[e] = 0.f;
        }
        half8 ov;
#pragma unroll
        for (int e = 0; e < 8; ++e) ov[e] = (_Float16)o[e];
        *(half8*)&bufA[p * STR0 + 8 * j] = ov;
      }
    }
  }
  __syncthreads();

  // ---------------- MLP: wave = (m-tile, n-half) ----------------
  const int lane = t & 63;
  const int mt   = q & 1;
  const int nhf  = q >> 1;
  const int nl   = lane & 31;
  const int kh   = lane >> 5;
  const int row  = mt * 32 + nl;
  const int mrow = mt * 32;
  const int n0   = nhf * 64 + nl;
  const int n1   = n0 + 32;

  {  // layer 0: K=192, in bufA(str 200) -> out bufB
    float bi0 = b0[n0], bi1 = b0[n1];
    f16v a0, a1;
#pragma unroll
    for (int i = 0; i < 16; ++i) { a0[i] = bi0; a1[i] = bi1; }
#pragma unroll
    for (int hh = 0; hh < 2; ++hh) {   // 2 halves of 6 ksteps: caps B-regs at 48
      half8 B0[6], B1[6];
#pragma unroll
      for (int ks = 0; ks < 6; ++ks) {
        int kof = (6 * hh + ks) * 16 + kh * 8;
        B0[ks] = *(const half8*)(wt + n0 * KP0 + kof);
        B1[ks] = *(const half8*)(wt + n1 * KP0 + kof);
      }
#pragma unroll
      for (int ks = 0; ks < 6; ++ks) {
        int kof = (6 * hh + ks) * 16 + kh * 8;
        half8 A = *(const half8*)&bufA[row * STR0 + kof];
        a0 = __builtin_amdgcn_mfma_f32_32x32x16_f16(A, B0[ks], a0, 0, 0, 0);
        a1 = __builtin_amdgcn_mfma_f32_32x32x16_f16(A, B1[ks], a1, 0, 0, 0);
      }
    }
#pragma unroll
    for (int r = 0; r < 16; ++r) {
      int rr = mrow + (r & 3) + 8 * (r >> 2) + 4 * kh;
      float z0 = a0[r]; z0 = z0 > 0.f ? z0 : 0.01f * z0;
      float z1 = a1[r]; z1 = z1 > 0.f ? z1 : 0.01f * z1;
      bufB[rr * STR1 + n0] = (_Float16)z0;
      bufB[rr * STR1 + n1] = (_Float16)z1;
    }
  }
  __syncthreads();
  layer128(bufB, bufA, wt + 24576,         b1, row, n0, n1, kh, mrow);  // L1
  __syncthreads();
  layer128(bufA, bufB, wt + 24576 + 16384, b2, row, n0, n1, kh, mrow);  // L2
  __syncthreads();
  layer128(bufB, bufA, wt + 24576 + 32768, b3, row, n0, n1, kh, mrow);  // L3
  __syncthreads();

  // ---------------- layer 4: 128 -> 3, VALU fp32 ----------------
  if (t < 64) {
    const _Float16* h4 = &bufA[t * STR1];
    float y0 = b4[0], y1 = b4[1], y2 = b4[2];
#pragma unroll 4
    for (int kc = 0; kc < 16; ++kc) {
      half8 v = *(const half8*)(h4 + kc * 8);
#pragma unroll
      for (int e = 0; e < 8; ++e) {
        float vf = (float)v[e];
        int k = kc * 8 + e;
        y0 += vf * W4[k * 3 + 0];
        y1 += vf * W4[k * 3 + 1];
        y2 += vf * W4[k * 3 + 2];
      }
    }
    out[(size_t)gp * 3 + 0] = y0;
    out[(size_t)gp * 3 + 1] = y1;
    out[(size_t)gp * 3 + 2] = y2;
  }
}

extern "C" void kernel_launch(void* const* d_in, const int* in_sizes, int n_in,
                              void* d_out, int out_size, void* d_ws, size_t ws_size,
                              hipStream_t stream) {
  const float* UV  = (const float*)d_in[0];
  const float* FEA = (const float*)d_in[1];
  const float* W0  = (const float*)d_in[2];
  const float* b0  = (const float*)d_in[3];
  const float* W1  = (const float*)d_in[4];
  const float* b1  = (const float*)d_in[5];
  const float* W2  = (const float*)d_in[6];
  const float* b2  = (const float*)d_in[7];
  const float* W3  = (const float*)d_in[8];
  const float* b3  = (const float*)d_in[9];
  const float* W4  = (const float*)d_in[10];
  const float* b4  = (const float*)d_in[11];
  float* out = (float*)d_out;

  _Float16* wt  = (_Float16*)d_ws;
  _Float16* f16 = wt + 73728;                       // byte offset 147456
  const size_t need = 147456ull + (size_t)GN * GN * CELL * 2ull;  // ~58.9 MB
  const bool f16path = ws_size >= need;

  k_weights<<<288, 256, 0, stream>>>(W0, W1, W2, W3, wt);
  if (f16path) {
    k_feat<<<28672, 256, 0, stream>>>(FEA, f16);
    k_main<true><<<16384, 256, 0, stream>>>(UV, FEA, wt, f16, b0, b1, b2, b3, W4, b4, out);
  } else {
    k_main<false><<<16384, 256, 0, stream>>>(UV, FEA, wt, wt, b0, b1, b2, b3, W4, b4, out);
  }
}

// Round 2
// 747.475 us; speedup vs baseline: 1.1806x; 1.1806x over previous
//
#include <hip/hip_runtime.h>

// ReLU_Feat_Posenc: bilinear gather (512x512x100) + posenc(16 freq) + MLP 166->128x4->3
// R2: count-sort points by cell bin (iU0*32 + iV0/16) so each block's gather is
// L1/L2-local (R1 was MSHR-latency-bound: MfmaUtil 8.7%, VALUBusy 20%, HBM 9.6%).
// Also: X repacked to K=176 -> LDS 40KB -> 4 blocks/CU; interp in packed f16.

#define GN    512
#define CELL  112   // padded f16 feature vector per grid cell (224 B)
#define KP0   176   // K for layer 0: feat 0..99, posenc 100..165, zero 166..175
#define STR0  184   // LDS X stride (f16), row = 368 B (16B-aligned)
#define STR1  136   // LDS h stride (f16), row = 272 B
#define TP    64    // points per block
#define NBINS 16384

typedef _Float16 half8  __attribute__((ext_vector_type(8)));
typedef _Float16 half4v __attribute__((ext_vector_type(4)));
typedef float    f4     __attribute__((ext_vector_type(4)));
typedef float    f16v   __attribute__((ext_vector_type(16)));

// ws layout (bytes):
//   0        wt (f16): Wt0[128][176] + 3x Wt[128][128]  (71680 elems, reserve 147456)
//   147456   hist   int[16384]
//   212992   cursor int[16384]
//   278528   sorted float4[1048576]  (16 MB)
//   17055744 feat16 [512*512][112] f16 (58.7 MB)   total ~75.8 MB
// Fallback (ws < 75.8MB, >= 58.9MB): feat16 at 147456, no sort.

__global__ __launch_bounds__(256) void k_weights(
    const float* __restrict__ W0, const float* __restrict__ W1,
    const float* __restrict__ W2, const float* __restrict__ W3,
    _Float16* __restrict__ wt) {
  int t = blockIdx.x * 256 + threadIdx.x;  // 280 blocks -> 71680
  if (t < 22528) {                 // Wt0[n][k'], k' = X col order
    int n = t / 176, k = t - n * 176;
    float v;
    if (k < 100)      v = W0[(66 + k) * 128 + n];   // feat rows of W0
    else if (k < 166) v = W0[(k - 100) * 128 + n];  // posenc rows
    else              v = 0.0f;                     // K pad
    wt[t] = (_Float16)v;
  } else {
    int u = t - 22528;
    int l = u >> 14, r = u & 16383;
    int n = r >> 7, k = r & 127;
    const float* W = (l == 0) ? W1 : (l == 1) ? W2 : W3;
    wt[22528 + l * 16384 + n * 128 + k] = (_Float16)W[k * 128 + n];
  }
}

__global__ __launch_bounds__(256) void k_feat(const float* __restrict__ F,
                                              _Float16* __restrict__ out) {
  int e = blockIdx.x * 256 + threadIdx.x;  // 28672 blocks: cell*28 + j4
  int cell = e / 28, j4 = e - cell * 28;
  half4v o;
  if (j4 < 25) {
    f4 f = *(const f4*)(F + (size_t)cell * 100 + j4 * 4);
    o[0] = (_Float16)f[0]; o[1] = (_Float16)f[1];
    o[2] = (_Float16)f[2]; o[3] = (_Float16)f[3];
  } else {
    o[0] = o[1] = o[2] = o[3] = (_Float16)0.0f;
  }
  *(half4v*)(out + (size_t)cell * CELL + j4 * 4) = o;
}

__global__ __launch_bounds__(256) void k_zero(int* __restrict__ hist) {
  hist[blockIdx.x * 256 + threadIdx.x] = 0;   // 64 blocks
}

__device__ __forceinline__ int point_bin(float U, float V) {
  int iU0 = (int)floorf(511.0f * U);
  int iV0 = (int)floorf(511.0f * V);
  return iU0 * 32 + (iV0 >> 4);
}

__global__ __launch_bounds__(256) void k_hist(const float* __restrict__ UV,
                                              int* __restrict__ hist) {
  int i = blockIdx.x * 256 + threadIdx.x;     // 4096 blocks
  float2 uv = ((const float2*)UV)[i];
  atomicAdd(&hist[point_bin(uv.x, uv.y)], 1);
}

__global__ __launch_bounds__(256) void k_scan(const int* __restrict__ hist,
                                              int* __restrict__ cursor) {
  __shared__ int tmp[256];
  int t = threadIdx.x;
  int base = t * 64;
  int s = 0;
  for (int i = 0; i < 64; ++i) s += hist[base + i];
  tmp[t] = s;
  __syncthreads();
  for (int d = 1; d < 256; d <<= 1) {
    int v = (t >= d) ? tmp[t - d] : 0;
    __syncthreads();
    tmp[t] += v;
    __syncthreads();
  }
  int off = tmp[t] - s;   // exclusive prefix of this thread's chunk
  for (int i = 0; i < 64; ++i) {
    cursor[base + i] = off;
    off += hist[base + i];
  }
}

__global__ __launch_bounds__(256) void k_scatter(const float* __restrict__ UV,
                                                 int* __restrict__ cursor,
                                                 float4* __restrict__ sorted) {
  int i = blockIdx.x * 256 + threadIdx.x;     // 4096 blocks
  float2 uv = ((const float2*)UV)[i];
  int pos = atomicAdd(&cursor[point_bin(uv.x, uv.y)], 1);
  sorted[pos] = make_float4(uv.x, uv.y, __int_as_float(i), 0.0f);
}

__device__ __forceinline__ void layer128(const _Float16* in, _Float16* outb,
    const _Float16* __restrict__ Wt, const float* __restrict__ bv,
    int row, int n0, int n1, int kh, int mrow) {
  half8 B0[8], B1[8];
#pragma unroll
  for (int ks = 0; ks < 8; ++ks) {
    B0[ks] = *(const half8*)(Wt + n0 * 128 + ks * 16 + kh * 8);
    B1[ks] = *(const half8*)(Wt + n1 * 128 + ks * 16 + kh * 8);
  }
  float bi0 = bv[n0], bi1 = bv[n1];
  f16v a0, a1;
#pragma unroll
  for (int i = 0; i < 16; ++i) { a0[i] = bi0; a1[i] = bi1; }
#pragma unroll
  for (int ks = 0; ks < 8; ++ks) {
    half8 A = *(const half8*)(in + row * STR1 + ks * 16 + kh * 8);
    a0 = __builtin_amdgcn_mfma_f32_32x32x16_f16(A, B0[ks], a0, 0, 0, 0);
    a1 = __builtin_amdgcn_mfma_f32_32x32x16_f16(A, B1[ks], a1, 0, 0, 0);
  }
#pragma unroll
  for (int r = 0; r < 16; ++r) {   // C: col=lane&31, row=(r&3)+8*(r>>2)+4*kh
    int rr = mrow + (r & 3) + 8 * (r >> 2) + 4 * kh;
    float z0 = a0[r]; z0 = z0 > 0.f ? z0 : 0.01f * z0;
    float z1 = a1[r]; z1 = z1 > 0.f ? z1 : 0.01f * z1;
    outb[rr * STR1 + n0] = (_Float16)z0;
    outb[rr * STR1 + n1] = (_Float16)z1;
  }
}

// MODE: 0 = f32 features, unsorted; 1 = f16 features, unsorted; 2 = f16 + sorted
template <int MODE>
__global__ __launch_bounds__(256) void k_main(
    const float* __restrict__ UV, const float* __restrict__ FEA,
    const float4* __restrict__ sorted,
    const _Float16* __restrict__ wt, const _Float16* __restrict__ feat16,
    const float* __restrict__ b0, const float* __restrict__ b1,
    const float* __restrict__ b2, const float* __restrict__ b3,
    const float* __restrict__ W4, const float* __restrict__ b4,
    float* __restrict__ out) {
  __shared__ _Float16 bufA[TP * STR0] __attribute__((aligned(16)));  // 23552 B
  __shared__ _Float16 bufB[TP * STR1] __attribute__((aligned(16)));  // 17408 B
  const int t = threadIdx.x;
  const int p = t & 63;        // point within tile
  const int q = t >> 6;        // wave id
  float U, V;
  int oidx;
  if constexpr (MODE == 2) {
    float4 s4 = sorted[blockIdx.x * TP + p];
    U = s4.x; V = s4.y; oidx = __float_as_int(s4.z);
  } else {
    oidx = blockIdx.x * TP + p;
    float2 uv = ((const float2*)UV)[oidx];
    U = uv.x; V = uv.y;
  }

  // ---------------- posenc (cols 100..165) + pad zero (166..175) ----------------
  if (q == 0) {
    bufA[p * STR0 + 100] = (_Float16)U;
    bufA[p * STR0 + 101] = (_Float16)V;
#pragma unroll
    for (int c = 166; c < 176; ++c) bufA[p * STR0 + c] = (_Float16)0.0f;
  }
  const float inv2pi = 0.15915494309189535f;
  const float twopi  = 6.283185307179586f;
#pragma unroll
  for (int fi = 0; fi < 4; ++fi) {
    int f = 4 * q + fi;
    float kk = (float)(1 << f);
    float ru = kk * U * inv2pi; ru -= floorf(ru);
    float rv = kk * V * inv2pi; rv -= floorf(rv);
    float su = __sinf(ru * twopi), cu = __cosf(ru * twopi);
    float sv = __sinf(rv * twopi), cv = __cosf(rv * twopi);
    int cbase = p * STR0 + 102 + 4 * f;
    bufA[cbase + 0] = (_Float16)su;
    bufA[cbase + 1] = (_Float16)sv;
    bufA[cbase + 2] = (_Float16)cu;
    bufA[cbase + 3] = (_Float16)cv;
  }

  // ---------------- bilinear gather (cols 0..99) ----------------
  {
    float iu = 511.0f * U, iv = 511.0f * V;
    float fu0 = floorf(iu), fv0 = floorf(iv);
    int iU0 = (int)fu0, iV0 = (int)fv0;
    int iU1 = (int)ceilf(iu), iV1 = (int)ceilf(iv);
    float fu = iu - fu0, fv = iv - fv0;
    float w00 = (1.f - fu) * (1.f - fv);
    float w10 = fu * (1.f - fv);
    float w01 = (1.f - fu) * fv;
    float w11 = fu * fv;
    int j0 = 3 * q;
    int j1 = (q == 3) ? 13 : 3 * q + 3;   // chunks {0-2}{3-5}{6-8}{9-12}
    if constexpr (MODE >= 1) {
      const half8* c00 = (const half8*)(feat16 + (size_t)(iU0 * GN + iV0) * CELL);
      const half8* c01 = (const half8*)(feat16 + (size_t)(iU0 * GN + iV1) * CELL);
      const half8* c10 = (const half8*)(feat16 + (size_t)(iU1 * GN + iV0) * CELL);
      const half8* c11 = (const half8*)(feat16 + (size_t)(iU1 * GN + iV1) * CELL);
      _Float16 h00 = (_Float16)w00, h01 = (_Float16)w01;
      _Float16 h10 = (_Float16)w10, h11 = (_Float16)w11;
      half8 v00, v01, v10, v11;
#pragma unroll
      for (int e = 0; e < 8; ++e) { v00[e]=h00; v01[e]=h01; v10[e]=h10; v11[e]=h11; }
      for (int j = j0; j < j1; ++j) {
        half8 a = c00[j], b = c01[j], c = c10[j], d = c11[j];
        half8 o = a * v00 + b * v01 + c * v10 + d * v11;  // v_pk_fma_f16
        if (j < 12) {
          *(half8*)&bufA[p * STR0 + 8 * j] = o;
        } else {       // chunk 12: only cols 96..99 are real features
          half4v o4; o4[0]=o[0]; o4[1]=o[1]; o4[2]=o[2]; o4[3]=o[3];
          *(half4v*)&bufA[p * STR0 + 96] = o4;
        }
      }
    } else {
      const float* r00 = FEA + (size_t)(iU0 * GN + iV0) * 100;
      const float* r01 = FEA + (size_t)(iU0 * GN + iV1) * 100;
      const float* r10 = FEA + (size_t)(iU1 * GN + iV0) * 100;
      const float* r11 = FEA + (size_t)(iU1 * GN + iV1) * 100;
      for (int j = j0; j < j1; ++j) {
        if (j < 12) {
          float o[8];
#pragma unroll
          for (int hh = 0; hh < 2; ++hh) {
            f4 a = *(const f4*)(r00 + 8 * j + 4 * hh);
            f4 b = *(const f4*)(r01 + 8 * j + 4 * hh);
            f4 c = *(const f4*)(r10 + 8 * j + 4 * hh);
            f4 d = *(const f4*)(r11 + 8 * j + 4 * hh);
#pragma unroll
            for (int e = 0; e < 4; ++e)
              o[4 * hh + e] = w00 * a[e] + w01 * b[e] + w10 * c[e] + w11 * d[e];
          }
          half8 ov;
#pragma unroll
          for (int e = 0; e < 8; ++e) ov[e] = (_Float16)o[e];
          *(half8*)&bufA[p * STR0 + 8 * j] = ov;
        } else {
          f4 a = *(const f4*)(r00 + 96);
          f4 b = *(const f4*)(r01 + 96);
          f4 c = *(const f4*)(r10 + 96);
          f4 d = *(const f4*)(r11 + 96);
          half4v o4;
#pragma unroll
          for (int e = 0; e < 4; ++e)
            o4[e] = (_Float16)(w00 * a[e] + w01 * b[e] + w10 * c[e] + w11 * d[e]);
          *(half4v*)&bufA[p * STR0 + 96] = o4;
        }
      }
    }
  }
  __syncthreads();

  // ---------------- MLP: wave = (m-tile, n-half) ----------------
  const int lane = t & 63;
  const int mt   = q & 1;
  const int nhf  = q >> 1;
  const int nl   = lane & 31;
  const int kh   = lane >> 5;
  const int row  = mt * 32 + nl;
  const int mrow = mt * 32;
  const int n0   = nhf * 64 + nl;
  const int n1   = n0 + 32;

  {  // layer 0: K=176 (11 ksteps), in bufA(str 184) -> out bufB
    float bi0 = b0[n0], bi1 = b0[n1];
    f16v a0, a1;
#pragma unroll
    for (int i = 0; i < 16; ++i) { a0[i] = bi0; a1[i] = bi1; }
#pragma unroll
    for (int hh = 0; hh < 2; ++hh) {   // 6 + 5 ksteps: caps live B-regs
      const int kcnt = hh ? 5 : 6;
      half8 B0[6], B1[6];
#pragma unroll
      for (int ks = 0; ks < kcnt; ++ks) {
        int kof = (6 * hh + ks) * 16 + kh * 8;
        B0[ks] = *(const half8*)(wt + n0 * KP0 + kof);
        B1[ks] = *(const half8*)(wt + n1 * KP0 + kof);
      }
#pragma unroll
      for (int ks = 0; ks < kcnt; ++ks) {
        int kof = (6 * hh + ks) * 16 + kh * 8;
        half8 A = *(const half8*)&bufA[row * STR0 + kof];
        a0 = __builtin_amdgcn_mfma_f32_32x32x16_f16(A, B0[ks], a0, 0, 0, 0);
        a1 = __builtin_amdgcn_mfma_f32_32x32x16_f16(A, B1[ks], a1, 0, 0, 0);
      }
    }
#pragma unroll
    for (int r = 0; r < 16; ++r) {
      int rr = mrow + (r & 3) + 8 * (r >> 2) + 4 * kh;
      float z0 = a0[r]; z0 = z0 > 0.f ? z0 : 0.01f * z0;
      float z1 = a1[r]; z1 = z1 > 0.f ? z1 : 0.01f * z1;
      bufB[rr * STR1 + n0] = (_Float16)z0;
      bufB[rr * STR1 + n1] = (_Float16)z1;
    }
  }
  __syncthreads();
  layer128(bufB, bufA, wt + 22528,         b1, row, n0, n1, kh, mrow);  // L1
  __syncthreads();
  layer128(bufA, bufB, wt + 22528 + 16384, b2, row, n0, n1, kh, mrow);  // L2
  __syncthreads();
  layer128(bufB, bufA, wt + 22528 + 32768, b3, row, n0, n1, kh, mrow);  // L3
  __syncthreads();

  // ---------------- layer 4: 128 -> 3, VALU fp32 ----------------
  if (t < 64) {
    const _Float16* h4 = &bufA[t * STR1];
    float y0 = b4[0], y1 = b4[1], y2 = b4[2];
#pragma unroll 4
    for (int kc = 0; kc < 16; ++kc) {
      half8 v = *(const half8*)(h4 + kc * 8);
#pragma unroll
      for (int e = 0; e < 8; ++e) {
        float vf = (float)v[e];
        int k = kc * 8 + e;
        y0 += vf * W4[k * 3 + 0];
        y1 += vf * W4[k * 3 + 1];
        y2 += vf * W4[k * 3 + 2];
      }
    }
    out[(size_t)oidx * 3 + 0] = y0;
    out[(size_t)oidx * 3 + 1] = y1;
    out[(size_t)oidx * 3 + 2] = y2;
  }
}

extern "C" void kernel_launch(void* const* d_in, const int* in_sizes, int n_in,
                              void* d_out, int out_size, void* d_ws, size_t ws_size,
                              hipStream_t stream) {
  const float* UV  = (const float*)d_in[0];
  const float* FEA = (const float*)d_in[1];
  const float* W0  = (const float*)d_in[2];
  const float* b0  = (const float*)d_in[3];
  const float* W1  = (const float*)d_in[4];
  const float* b1  = (const float*)d_in[5];
  const float* W2  = (const float*)d_in[6];
  const float* b2  = (const float*)d_in[7];
  const float* W3  = (const float*)d_in[8];
  const float* b3  = (const float*)d_in[9];
  const float* W4  = (const float*)d_in[10];
  const float* b4  = (const float*)d_in[11];
  float* out = (float*)d_out;

  char* ws = (char*)d_ws;
  _Float16* wt = (_Float16*)ws;
  const size_t featBytes = (size_t)GN * GN * CELL * 2ull;   // 58,720,256
  const size_t needSort  = 17055744ull + featBytes;          // ~75.8 MB
  const size_t needF16   = 147456ull + featBytes;            // ~58.9 MB

  k_weights<<<280, 256, 0, stream>>>(W0, W1, W2, W3, wt);
  if (ws_size >= needSort) {
    int*    hist    = (int*)(ws + 147456);
    int*    cursor  = (int*)(ws + 212992);
    float4* sorted  = (float4*)(ws + 278528);
    _Float16* f16   = (_Float16*)(ws + 17055744);
    k_feat<<<28672, 256, 0, stream>>>(FEA, f16);
    k_zero<<<64, 256, 0, stream>>>(hist);
    k_hist<<<4096, 256, 0, stream>>>(UV, hist);
    k_scan<<<1, 256, 0, stream>>>(hist, cursor);
    k_scatter<<<4096, 256, 0, stream>>>(UV, cursor, sorted);
    k_main<2><<<16384, 256, 0, stream>>>(UV, FEA, sorted, wt, f16,
                                         b0, b1, b2, b3, W4, b4, out);
  } else if (ws_size >= needF16) {
    _Float16* f16 = (_Float16*)(ws + 147456);
    k_feat<<<28672, 256, 0, stream>>>(FEA, f16);
    k_main<1><<<16384, 256, 0, stream>>>(UV, FEA, nullptr, wt, f16,
                                         b0, b1, b2, b3, W4, b4, out);
  } else {
    k_main<0><<<16384, 256, 0, stream>>>(UV, FEA, nullptr, wt, nullptr,
                                         b0, b1, b2, b3, W4, b4, out);
  }
}

// Round 3
// 660.187 us; speedup vs baseline: 1.3367x; 1.1322x over previous
//
#include <hip/hip_runtime.h>

// ReLU_Feat_Posenc: bilinear gather (512x512x100) + posenc(16 freq) + MLP 166->128x4->3
// R3: (1) weights stored in MFMA-fragment order -> coalesced lane*16 loads
//     (R2 was TA-bound: divergent weight loads = 64 cache lines/instr ~ 480us);
//     (2) transposed activations (h^T = W^T x^T): weights = A operand (regs),
//     C-layout reg-quads = contiguous out-channels -> ds_write_b64 epilogue;
//     (3) hierarchical scan replaces single-block k_scan.

#define GN    512
#define CELL  112   // padded f16 feature vector per grid cell (224 B)
#define KP0   176   // K for layer 0: feat 0..99, posenc 100..165, zero 166..175
#define STR0  184   // LDS X stride (f16), row = 368 B (16B-aligned)
#define STR1  136   // LDS G stride (f16), row = 272 B
#define TP    64    // points per block

// wt fragment-order offsets (f16 elems)
#define WOFF1 22528
#define WOFF2 38912
#define WOFF3 55296

typedef _Float16 half8  __attribute__((ext_vector_type(8)));
typedef _Float16 half4v __attribute__((ext_vector_type(4)));
typedef float    f4     __attribute__((ext_vector_type(4)));
typedef float    f16v   __attribute__((ext_vector_type(16)));

// ws layout (bytes):
//   0         wt fragment-order f16 (143360, reserve 147456)
//   147456    hist    int[16384]
//   212992    binoff  int[16384]  (per-block-exclusive offsets; atomic cursor)
//   278528    bsum    int[64]
//   278784    bbase   int[64]
//   294912    sorted  float4[1048576] (16 MB)
//   17072128  feat16  [512*512][112] f16 (58.7 MB)   total ~75.8 MB

__global__ __launch_bounds__(256) void k_weights(
    const float* __restrict__ W0, const float* __restrict__ W1,
    const float* __restrict__ W2, const float* __restrict__ W3,
    _Float16* __restrict__ wt) {
  int t = blockIdx.x * 256 + threadIdx.x;  // 280 blocks -> 71680
  float v;
  if (t < 22528) {            // L0 frags: ((ot*11+ks)*64+l)*8+j
    int j = t & 7, l = (t >> 3) & 63, g = t >> 9;
    int ks = g % 11;          // ot = g/11 unused: n needs ot
    int ot = g / 11;
    int k = 16 * ks + 8 * (l >> 5) + j;       // X column
    int n = ot * 32 + (l & 31);               // out channel
    if (k < 100)      v = W0[(66 + k) * 128 + n];   // feat rows of W0
    else if (k < 166) v = W0[(k - 100) * 128 + n];  // posenc rows
    else              v = 0.0f;                     // K pad
  } else {                    // L1-3 frags: ((ot*8+ks)*64+l)*8+j
    int u = t - 22528;
    int layer = u >> 14, r = u & 16383;
    int j = r & 7, l = (r >> 3) & 63, ks = (r >> 9) & 7, ot = r >> 12;
    int k = 16 * ks + 8 * (l >> 5) + j;
    int n = ot * 32 + (l & 31);
    const float* W = (layer == 0) ? W1 : (layer == 1) ? W2 : W3;
    v = W[k * 128 + n];
  }
  wt[t] = (_Float16)v;
}

__global__ __launch_bounds__(256) void k_feat(const float* __restrict__ F,
                                              _Float16* __restrict__ out) {
  int e = blockIdx.x * 256 + threadIdx.x;  // 28672 blocks: cell*28 + j4
  int cell = e / 28, j4 = e - cell * 28;
  half4v o;
  if (j4 < 25) {
    f4 f = *(const f4*)(F + (size_t)cell * 100 + j4 * 4);
    o[0] = (_Float16)f[0]; o[1] = (_Float16)f[1];
    o[2] = (_Float16)f[2]; o[3] = (_Float16)f[3];
  } else {
    o[0] = o[1] = o[2] = o[3] = (_Float16)0.0f;
  }
  *(half4v*)(out + (size_t)cell * CELL + j4 * 4) = o;
}

__device__ __forceinline__ int point_bin(float U, float V) {
  int iU0 = (int)floorf(511.0f * U);
  int iV0 = (int)floorf(511.0f * V);
  return iU0 * 32 + (iV0 >> 4);
}

__global__ __launch_bounds__(256) void k_hist(const float* __restrict__ UV,
                                              int* __restrict__ hist) {
  int i = blockIdx.x * 256 + threadIdx.x;     // 4096 blocks
  float2 uv = ((const float2*)UV)[i];
  atomicAdd(&hist[point_bin(uv.x, uv.y)], 1);
}

__global__ __launch_bounds__(256) void k_scanA(const int* __restrict__ hist,
                                               int* __restrict__ binoff,
                                               int* __restrict__ bsum) {
  __shared__ int s[256];
  int t = threadIdx.x, g = blockIdx.x * 256 + t;   // 64 blocks
  int v = hist[g];
  s[t] = v;
  __syncthreads();
  for (int d = 1; d < 256; d <<= 1) {
    int x = (t >= d) ? s[t - d] : 0;
    __syncthreads();
    s[t] += x;
    __syncthreads();
  }
  binoff[g] = s[t] - v;            // exclusive within block
  if (t == 255) bsum[blockIdx.x] = s[t];
}

__global__ __launch_bounds__(64) void k_scanB(const int* __restrict__ bsum,
                                              int* __restrict__ bbase) {
  __shared__ int s[64];
  int t = threadIdx.x;
  int v = bsum[t];
  s[t] = v;
  __syncthreads();
  for (int d = 1; d < 64; d <<= 1) {
    int x = (t >= d) ? s[t - d] : 0;
    __syncthreads();
    s[t] += x;
    __syncthreads();
  }
  bbase[t] = s[t] - v;             // exclusive across blocks
}

__global__ __launch_bounds__(256) void k_scatter(const float* __restrict__ UV,
                                                 int* __restrict__ binoff,
                                                 const int* __restrict__ bbase,
                                                 float4* __restrict__ sorted) {
  int i = blockIdx.x * 256 + threadIdx.x;     // 4096 blocks
  float2 uv = ((const float2*)UV)[i];
  int bin = point_bin(uv.x, uv.y);
  int pos = atomicAdd(&binoff[bin], 1) + bbase[bin >> 8];
  sorted[pos] = make_float4(uv.x, uv.y, __int_as_float(i), 0.0f);
}

// Transposed layer for K=128: G_out = leaky(W^T G_in + b), G layouts [point][k]
__device__ __forceinline__ void layerT(const _Float16* Gin, _Float16* Gout,
    const _Float16* __restrict__ wf, const float* __restrict__ bp,
    int lane, int ot) {
  const int nl = lane & 31, kh = lane >> 5;
  half8 A[8];
#pragma unroll
  for (int ks = 0; ks < 8; ++ks)    // coalesced: base + lane*16B
    A[ks] = *(const half8*)(wf + ((ot * 8 + ks) * 64 + lane) * 8);
  f4 bf[4];
#pragma unroll
  for (int g = 0; g < 4; ++g)
    bf[g] = *(const f4*)(bp + ot * 32 + 4 * kh + 8 * g);
  f16v a0, a1;
#pragma unroll
  for (int r = 0; r < 16; ++r) { float bv = bf[r >> 2][r & 3]; a0[r] = bv; a1[r] = bv; }
#pragma unroll
  for (int ks = 0; ks < 8; ++ks) {
    half8 B0 = *(const half8*)(Gin + nl * STR1 + ks * 16 + kh * 8);
    half8 B1 = *(const half8*)(Gin + (32 + nl) * STR1 + ks * 16 + kh * 8);
    a0 = __builtin_amdgcn_mfma_f32_32x32x16_f16(A[ks], B0, a0, 0, 0, 0);
    a1 = __builtin_amdgcn_mfma_f32_32x32x16_f16(A[ks], B1, a1, 0, 0, 0);
  }
#pragma unroll
  for (int g = 0; g < 4; ++g) {     // reg-quad = 4 contiguous out-channels
    half4v h0, h1;
#pragma unroll
    for (int i = 0; i < 4; ++i) {
      float z0 = a0[4 * g + i]; z0 = z0 > 0.f ? z0 : 0.01f * z0;
      float z1 = a1[4 * g + i]; z1 = z1 > 0.f ? z1 : 0.01f * z1;
      h0[i] = (_Float16)z0; h1[i] = (_Float16)z1;
    }
    int col = ot * 32 + 4 * kh + 8 * g;
    *(half4v*)(Gout + nl * STR1 + col) = h0;          // ds_write_b64
    *(half4v*)(Gout + (32 + nl) * STR1 + col) = h1;
  }
}

// MODE: 1 = f16 features, unsorted; 2 = f16 + sorted
template <int MODE>
__global__ __launch_bounds__(256, 4) void k_main(
    const float* __restrict__ UV, const float4* __restrict__ sorted,
    const _Float16* __restrict__ wt, const _Float16* __restrict__ feat16,
    const float* __restrict__ b0, const float* __restrict__ b1,
    const float* __restrict__ b2, const float* __restrict__ b3,
    const float* __restrict__ W4, const float* __restrict__ b4,
    float* __restrict__ out) {
  __shared__ _Float16 bufA[TP * STR0] __attribute__((aligned(16)));  // 23552 B
  __shared__ _Float16 bufB[TP * STR1] __attribute__((aligned(16)));  // 17408 B
  const int t = threadIdx.x;
  const int p = t & 63;        // point within tile
  const int q = t >> 6;        // wave id
  float U, V;
  int oidx;
  if constexpr (MODE == 2) {
    float4 s4 = sorted[blockIdx.x * TP + p];
    U = s4.x; V = s4.y; oidx = __float_as_int(s4.z);
  } else {
    oidx = blockIdx.x * TP + p;
    float2 uv = ((const float2*)UV)[oidx];
    U = uv.x; V = uv.y;
  }

  // ---------------- posenc (cols 100..165) + pad zero + oidx stash ----------
  if (q == 0) {
    bufA[p * STR0 + 100] = (_Float16)U;
    bufA[p * STR0 + 101] = (_Float16)V;
#pragma unroll
    for (int c = 166; c < 176; ++c) bufA[p * STR0 + c] = (_Float16)0.0f;
    *(int*)&bufB[p * STR1 + 128] = oidx;   // survives: layers write cols 0..127
  }
  const float inv2pi = 0.15915494309189535f;
  const float twopi  = 6.283185307179586f;
#pragma unroll
  for (int fi = 0; fi < 4; ++fi) {
    int f = 4 * q + fi;
    float kk = (float)(1 << f);
    float ru = kk * U * inv2pi; ru -= floorf(ru);
    float rv = kk * V * inv2pi; rv -= floorf(rv);
    float su = __sinf(ru * twopi), cu = __cosf(ru * twopi);
    float sv = __sinf(rv * twopi), cv = __cosf(rv * twopi);
    int cbase = p * STR0 + 102 + 4 * f;
    bufA[cbase + 0] = (_Float16)su;
    bufA[cbase + 1] = (_Float16)sv;
    bufA[cbase + 2] = (_Float16)cu;
    bufA[cbase + 3] = (_Float16)cv;
  }

  // ---------------- bilinear gather (cols 0..99) ----------------
  {
    float iu = 511.0f * U, iv = 511.0f * V;
    float fu0 = floorf(iu), fv0 = floorf(iv);
    int iU0 = (int)fu0, iV0 = (int)fv0;
    int iU1 = (int)ceilf(iu), iV1 = (int)ceilf(iv);
    float fu = iu - fu0, fv = iv - fv0;
    float w00 = (1.f - fu) * (1.f - fv);
    float w10 = fu * (1.f - fv);
    float w01 = (1.f - fu) * fv;
    float w11 = fu * fv;
    int j0 = 3 * q;
    int j1 = (q == 3) ? 13 : 3 * q + 3;   // chunks {0-2}{3-5}{6-8}{9-12}
    const half8* c00 = (const half8*)(feat16 + (size_t)(iU0 * GN + iV0) * CELL);
    const half8* c01 = (const half8*)(feat16 + (size_t)(iU0 * GN + iV1) * CELL);
    const half8* c10 = (const half8*)(feat16 + (size_t)(iU1 * GN + iV0) * CELL);
    const half8* c11 = (const half8*)(feat16 + (size_t)(iU1 * GN + iV1) * CELL);
    _Float16 h00 = (_Float16)w00, h01 = (_Float16)w01;
    _Float16 h10 = (_Float16)w10, h11 = (_Float16)w11;
    half8 v00, v01, v10, v11;
#pragma unroll
    for (int e = 0; e < 8; ++e) { v00[e]=h00; v01[e]=h01; v10[e]=h10; v11[e]=h11; }
    for (int j = j0; j < j1; ++j) {
      half8 a = c00[j], b = c01[j], c = c10[j], d = c11[j];
      half8 o = a * v00 + b * v01 + c * v10 + d * v11;  // v_pk_fma_f16
      if (j < 12) {
        *(half8*)&bufA[p * STR0 + 8 * j] = o;
      } else {       // chunk 12: only cols 96..99 are real features
        half4v o4; o4[0]=o[0]; o4[1]=o[1]; o4[2]=o[2]; o4[3]=o[3];
        *(half4v*)&bufA[p * STR0 + 96] = o4;
      }
    }
  }
  __syncthreads();

  // ---------------- MLP, transposed: wave q = out-quarter ot ----------------
  const int lane = t & 63;
  const int ot   = q;
  const int nl   = lane & 31;
  const int kh   = lane >> 5;

  {  // layer 0: K=176 (11 ksteps), bufA(STR0) -> bufB
    half8 A[11];
#pragma unroll
    for (int ks = 0; ks < 11; ++ks)
      A[ks] = *(const half8*)(wt + ((ot * 11 + ks) * 64 + lane) * 8);
    f4 bf[4];
#pragma unroll
    for (int g = 0; g < 4; ++g)
      bf[g] = *(const f4*)(b0 + ot * 32 + 4 * kh + 8 * g);
    f16v a0, a1;
#pragma unroll
    for (int r = 0; r < 16; ++r) { float bv = bf[r >> 2][r & 3]; a0[r] = bv; a1[r] = bv; }
#pragma unroll
    for (int ks = 0; ks < 11; ++ks) {
      half8 B0 = *(const half8*)&bufA[nl * STR0 + ks * 16 + kh * 8];
      half8 B1 = *(const half8*)&bufA[(32 + nl) * STR0 + ks * 16 + kh * 8];
      a0 = __builtin_amdgcn_mfma_f32_32x32x16_f16(A[ks], B0, a0, 0, 0, 0);
      a1 = __builtin_amdgcn_mfma_f32_32x32x16_f16(A[ks], B1, a1, 0, 0, 0);
    }
#pragma unroll
    for (int g = 0; g < 4; ++g) {
      half4v h0, h1;
#pragma unroll
      for (int i = 0; i < 4; ++i) {
        float z0 = a0[4 * g + i]; z0 = z0 > 0.f ? z0 : 0.01f * z0;
        float z1 = a1[4 * g + i]; z1 = z1 > 0.f ? z1 : 0.01f * z1;
        h0[i] = (_Float16)z0; h1[i] = (_Float16)z1;
      }
      int col = ot * 32 + 4 * kh + 8 * g;
      *(half4v*)&bufB[nl * STR1 + col] = h0;
      *(half4v*)&bufB[(32 + nl) * STR1 + col] = h1;
    }
  }
  __syncthreads();
  layerT(bufB, bufA, wt + WOFF1, b1, lane, ot);  __syncthreads();  // L1
  layerT(bufA, bufB, wt + WOFF2, b2, lane, ot);  __syncthreads();  // L2
  layerT(bufB, bufA, wt + WOFF3, b3, lane, ot);  __syncthreads();  // L3

  // ---------------- layer 4: 128 -> 3, 4 threads/point + shuffle ----------
  {
    int pp = t >> 2, qt = t & 3;
    const _Float16* h4 = &bufA[pp * STR1 + qt * 32];
    float y0 = 0.f, y1 = 0.f, y2 = 0.f;
#pragma unroll
    for (int c = 0; c < 4; ++c) {
      half8 v = *(const half8*)(h4 + 8 * c);
#pragma unroll
      for (int e = 0; e < 8; ++e) {
        float vf = (float)v[e];
        int k = qt * 32 + 8 * c + e;
        y0 += vf * W4[k * 3 + 0];
        y1 += vf * W4[k * 3 + 1];
        y2 += vf * W4[k * 3 + 2];
      }
    }
    y0 += __shfl_xor(y0, 1); y0 += __shfl_xor(y0, 2);
    y1 += __shfl_xor(y1, 1); y1 += __shfl_xor(y1, 2);
    y2 += __shfl_xor(y2, 1); y2 += __shfl_xor(y2, 2);
    if (qt == 0) {
      int op;
      if constexpr (MODE == 2) op = *(const int*)&bufB[pp * STR1 + 128];
      else                     op = blockIdx.x * TP + pp;
      out[(size_t)op * 3 + 0] = y0 + b4[0];
      out[(size_t)op * 3 + 1] = y1 + b4[1];
      out[(size_t)op * 3 + 2] = y2 + b4[2];
    }
  }
}

extern "C" void kernel_launch(void* const* d_in, const int* in_sizes, int n_in,
                              void* d_out, int out_size, void* d_ws, size_t ws_size,
                              hipStream_t stream) {
  const float* UV  = (const float*)d_in[0];
  const float* FEA = (const float*)d_in[1];
  const float* W0  = (const float*)d_in[2];
  const float* b0  = (const float*)d_in[3];
  const float* W1  = (const float*)d_in[4];
  const float* b1  = (const float*)d_in[5];
  const float* W2  = (const float*)d_in[6];
  const float* b2  = (const float*)d_in[7];
  const float* W3  = (const float*)d_in[8];
  const float* b3  = (const float*)d_in[9];
  const float* W4  = (const float*)d_in[10];
  const float* b4  = (const float*)d_in[11];
  float* out = (float*)d_out;

  char* ws = (char*)d_ws;
  _Float16* wt = (_Float16*)ws;
  int*    hist   = (int*)(ws + 147456);
  int*    binoff = (int*)(ws + 212992);
  int*    bsum   = (int*)(ws + 278528);
  int*    bbase  = (int*)(ws + 278784);
  float4* sorted = (float4*)(ws + 294912);
  _Float16* f16s = (_Float16*)(ws + 17072128);
  _Float16* f16u = (_Float16*)(ws + 147456);

  const size_t featBytes = (size_t)GN * GN * CELL * 2ull;   // 58,720,256
  const size_t needSort  = 17072128ull + featBytes;          // ~75.8 MB
  const size_t needF16   = 147456ull + featBytes;            // ~58.9 MB

  k_weights<<<280, 256, 0, stream>>>(W0, W1, W2, W3, wt);
  if (ws_size >= needSort) {
    k_feat<<<28672, 256, 0, stream>>>(FEA, f16s);
    hipMemsetAsync(hist, 0, 65536, stream);
    k_hist<<<4096, 256, 0, stream>>>(UV, hist);
    k_scanA<<<64, 256, 0, stream>>>(hist, binoff, bsum);
    k_scanB<<<1, 64, 0, stream>>>(bsum, bbase);
    k_scatter<<<4096, 256, 0, stream>>>(UV, binoff, bbase, sorted);
    k_main<2><<<16384, 256, 0, stream>>>(UV, sorted, wt, f16s,
                                         b0, b1, b2, b3, W4, b4, out);
  } else {
    k_feat<<<28672, 256, 0, stream>>>(FEA, f16u);
    k_main<1><<<16384, 256, 0, stream>>>(UV, nullptr, wt, f16u,
                                         b0, b1, b2, b3, W4, b4, out);
  }
}